// Round 13
// baseline (363.019 us; speedup 1.0000x reference)
//
#include <hip/hip_runtime.h>
#include <hip/hip_bf16.h>

typedef _Float16 f16x8 __attribute__((ext_vector_type(8)));
typedef float f32x4  __attribute__((ext_vector_type(4)));
typedef int   i32x4  __attribute__((ext_vector_type(4)));
typedef unsigned short u16x4 __attribute__((ext_vector_type(4)));

#define T_STEPS 40
#define BATCH   256
#define S2LO    0.000244140625f   // 2^-12, exact
// fc1 int8 3-plane quantization: w ~= WQ_S*(q2*16384 + q1*128 + q0)
#define WQ_INV  (2080768.0f/0.103f)   // 1/WQ_S ; 2080768 = 127*16384
#define WQ_S    (0.103f/2080768.0f)

__device__ __forceinline__ unsigned short f2h_bits(float f) {
    union { _Float16 h; unsigned short u; } c; c.h = (_Float16)f; return c.u;
}

// norse LIF step, pinned to mul-then-add fp32 order.
__device__ __forceinline__ float lif_update(float inp, float& v, float& i, float vth) {
    float vd = __fadd_rn(v, __fmul_rn(0.1f, __fsub_rn(i, v)));
    float id = __fmul_rn(0.8f, i);
    float z  = (vd > vth) ? 1.0f : 0.0f;
    v = (vd > vth) ? 0.0f : vd;
    i = __fadd_rn(id, inp);
    return z;
}

__device__ __forceinline__ void llds16(const void* g, void* l) {
    __builtin_amdgcn_global_load_lds(
        (const __attribute__((address_space(1))) unsigned int*)g,
        (__attribute__((address_space(3))) unsigned int*)l, 16, 0, 0);
}

// ---------------------------------------------------------------------------
// Kernel 1 (v7, R11-proven): conv1 + LIF0 + 2x2 avgpool. Row-range staging
// (<=8 of 28 rows per block), full-line wave stores, quad-buffered 2-deep
// register pipe.
// ---------------------------------------------------------------------------
__global__ __launch_bounds__(512) void k_conv1(
    const float* __restrict__ x,             // [T,B,784] fp32
    const float* __restrict__ w1,            // [20,1,3,3] fp32
    unsigned char* __restrict__ s0)          // [T,B,4096] u8
{
    const int b    = blockIdx.y;
    const int tid  = threadIdx.x;
    const int cell = blockIdx.x*512 + tid;   // 0..4095 == byte offset in row
    const int pos  = cell / 24;              // 0..170
    const int oc   = cell - pos*24;          // 0..23
    const bool active = (pos < 169) && (oc < 20);
    const int pr   = pos / 13, q = pos - pr*13;
    const int c0   = 2*q;

    // block-uniform staged row range
    const int p0    = (blockIdx.x*512) / 24;
    const int pmaxv = min((blockIdx.x*512 + 511) / 24, 168);
    const int rlo   = 2*(p0/13);                          // first row staged
    const int rhi   = min(2*(pmaxv/13) + 3, 27);          // last row staged
    const int nf4   = (rhi - rlo + 1) * 7;                // float4s (<=56)
    const int rloc  = 2*pr - rlo;                         // local row base

    __shared__ __align__(16) float xl[4][224];
    const bool stager = tid < nf4;

    float wr[9];
    if (active) {
        #pragma unroll
        for (int j = 0; j < 9; ++j) wr[j] = w1[oc*9 + j];
    }
    float vs[2][2], is[2][2];
    #pragma unroll
    for (int dr = 0; dr < 2; ++dr)
        #pragma unroll
        for (int dc = 0; dc < 2; ++dc) { vs[dr][dc] = 0.f; is[dr][dc] = 0.f; }

    float4 pA, pB;
    if (stager) {
        const float* xr = x + (size_t)b*784 + rlo*28;
        *(float4*)&xl[0][tid*4] = ((const float4*)(xr + 0*BATCH*784))[tid];
        *(float4*)&xl[1][tid*4] = ((const float4*)(xr + 1ull*BATCH*784))[tid];
        pA = ((const float4*)(xr + 2ull*BATCH*784))[tid];
        pB = ((const float4*)(xr + 3ull*BATCH*784))[tid];
    }

    for (int t = 0; t < T_STEPS; ++t) {
        __syncthreads();   // buf[t&3] ready; buf[(t+2)&3] consumers done
        if (stager) {
            if (t + 2 < T_STEPS) *(float4*)&xl[(t+2)&3][tid*4] = pA;
            pA = pB;
            if (t + 4 < T_STEPS)
                pB = ((const float4*)(x + (size_t)((t+4)*BATCH + b)*784 + rlo*28))[tid];
        }
        const float* xc = xl[t&3];
        size_t base = (size_t)(t*BATCH + b) * 4096;

        unsigned char outb = 0;
        if (active) {
            float tle[4][4];
            #pragma unroll
            for (int r = 0; r < 4; ++r) {
                float2 t01 = *(const float2*)&xc[(rloc + r)*28 + c0];
                float2 t23 = *(const float2*)&xc[(rloc + r)*28 + c0 + 2];
                tle[r][0] = t01.x; tle[r][1] = t01.y;
                tle[r][2] = t23.x; tle[r][3] = t23.y;
            }
            int zsum = 0;
            #pragma unroll
            for (int dr = 0; dr < 2; ++dr)
                #pragma unroll
                for (int dc = 0; dc < 2; ++dc) {
                    float acc = 0.f;
                    #pragma unroll
                    for (int kr = 0; kr < 3; ++kr)
                        #pragma unroll
                        for (int kc = 0; kc < 3; ++kc)
                            acc += tle[dr+kr][dc+kc] * wr[kr*3+kc];
                    float z = lif_update(acc, vs[dr][dc], is[dr][dc], 0.2f);
                    zsum += (z > 0.5f) ? 1 : 0;
                }
            outb = (unsigned char)zsum;
        }
        s0[base + cell] = outb;   // wave = 64 consecutive bytes = 1 full line
    }
}

// ---------------------------------------------------------------------------
// Kernel 2 (v4): conv2 via fp16 MFMA + FUSED weight pack.
// conv blocks (bid < 1024): quad-major mapping (b = bid&255, quad = bid>>8),
//   w2m hoisted to registers (R12-proven).
// pack blocks (bid >= 1024): exactly 256 blocks = 1/CU. conv2 is 4 blocks/CU
//   x 31 KB -> a 5th block fits (155 KB LDS, 20 waves) and CO-RESIDES from
//   t=0, so pack's ~6us hides under conv2's ~45us window (unlike R10's
//   conv1 fusion, which extended a fully-resident grid into a serial tail).
//   W1q/W2 live OUTSIDE the s0 overlay (s0 still live during conv2).
// Weights carry the exact x0.25 pool scale. z1: U8 SPIKES {0,1}, row stride
// 6272 (=49*128), [oc50][pos124] + 72B pad.
// ---------------------------------------------------------------------------
__global__ __launch_bounds__(256, 4) void k_conv2(
    const unsigned char* __restrict__ s0,    // [T,B,4096] u8
    const float* __restrict__ w2,            // [50,20,3,3] fp32
    unsigned char* __restrict__ z1,          // [T,B,6272] u8 spikes
    const float* __restrict__ wf1,           // [500,6050] fp32
    const float* __restrict__ wf2,           // [200,500] fp32
    signed char* __restrict__ W1,            // 3 i8 planes x 3,211,264
    unsigned short* __restrict__ W2)         // fp16 hi/lo x 131,072
{
    if (blockIdx.x >= 1024) {
        // ---- fused weight pack: 256 blocks x 256 threads, grid-strided ----
        int pid = blockIdx.x - 1024;
        for (int idx = pid*256 + threadIdx.x; idx < 3342336; idx += 65536) {
            if (idx < 3211264) {                       // fc1: 512*6272
                int n = idx / 6272, k = idx - n*6272;
                int oc = k / 124, pos = k - oc*124;
                float v = (n < 500 && oc < 50 && pos < 121)
                          ? wf1[n*6050 + oc*121 + pos] : 0.f;
                float a = v * WQ_INV;
                int q2 = __float2int_rn(a * (1.0f/16384.0f));
                q2 = q2 < -127 ? -127 : (q2 > 127 ? 127 : q2);
                float r1 = a - (float)q2 * 16384.0f;
                int q1 = __float2int_rn(r1 * (1.0f/128.0f));
                q1 = q1 < -127 ? -127 : (q1 > 127 ? 127 : q1);
                float r0 = r1 - (float)q1 * 128.0f;
                int q0 = __float2int_rn(r0);
                q0 = q0 < -127 ? -127 : (q0 > 127 ? 127 : q0);
                W1[idx]             = (signed char)q0;
                W1[idx + 3211264]   = (signed char)q1;
                W1[idx + 2*3211264] = (signed char)q2;
            } else {                                   // fc2 hi/lo fp16
                int i2 = idx - 3211264;
                int n = i2 >> 9, k = i2 & 511;
                float v = (n < 200 && k < 500) ? wf2[n*500 + k] : 0.f;
                _Float16 h = (_Float16)v;
                float r1 = (v - (float)h) * 4096.0f;
                union { _Float16 h; unsigned short u; } ch, cl;
                ch.h = h; cl.h = (_Float16)r1;
                W2[i2] = ch.u;
                W2[i2 + 131072] = cl.u;
            }
        }
        return;
    }

    const int b    = blockIdx.x & 255;       // quad-major (R12a)
    const int quad = blockIdx.x >> 8;
    const int tid  = threadIdx.x;
    const int wv   = tid >> 6;
    const int lane = tid & 63;
    const int l15  = lane & 15;
    const int kg   = lane >> 4;
    const int wm   = wv;           // 4 m-waves x 32 pos

    __shared__ __align__(16) unsigned short w2h[16*232];
    __shared__ __align__(16) unsigned short w2m[16*232];
    __shared__ __align__(16) unsigned short sIn[2*4096];   // fp16 double buffer

    for (int s = tid; s < 16*232; s += 256) {
        int ocw = s / 232, kk = s % 232;
        int g = kk / 24, ic = kk % 24;
        int oc = quad*16 + ocw;
        float val = 0.f;
        if (oc < 50 && g < 9 && ic < 20) val = 0.25f * w2[(oc*20 + ic)*9 + g];
        _Float16 h = (_Float16)val;
        float r1 = (val - (float)h) * 4096.0f;
        union { _Float16 h; unsigned short u; } ch, cm;
        ch.h = h; cm.h = (_Float16)r1;
        w2h[s] = ch.u;
        w2m[s] = cm.u;
    }

    f16x8 bfrH[7], bfrM[7];
    int addrA[2][7];
    #pragma unroll
    for (int mt = 0; mt < 2; ++mt) {
        int pos = wm*32 + mt*16 + l15;
        #pragma unroll
        for (int kt = 0; kt < 7; ++kt) {
            int k = kt*32 + kg*8;
            int g = k / 24, o = k - g*24;
            if (pos <= 120 && g <= 8) {
                int in_idx = pos + 2*(pos/11) + 13*(g/3) + (g % 3);
                addrA[mt][kt] = in_idx*48 + o*2;
            } else addrA[mt][kt] = 8128;   // elem 4064: zeroed tail
        }
    }

    // stage t=0 (u8 -> f16, exact small ints)
    {
        const unsigned char* srow = s0 + (size_t)(0*BATCH + b)*4096;
        uint4 raw = *(const uint4*)(srow + tid*16);
        unsigned short hv[16];
        #pragma unroll
        for (int w = 0; w < 4; ++w) {
            unsigned int u = ((const unsigned int*)&raw)[w];
            #pragma unroll
            for (int j = 0; j < 4; ++j)
                hv[w*4+j] = f2h_bits((float)((u >> (8*j)) & 0xFFu));
        }
        unsigned short* dst = sIn + tid*16;
        *(f16x8*)dst       = *(const f16x8*)&hv[0];
        *(f16x8*)(dst + 8) = *(const f16x8*)&hv[8];
    }
    __syncthreads();

    #pragma unroll
    for (int kt = 0; kt < 7; ++kt) {
        bfrH[kt] = *(const f16x8*)&w2h[l15*232 + kt*32 + kg*8];
        bfrM[kt] = *(const f16x8*)&w2m[l15*232 + kt*32 + kg*8];   // R12b hoist
    }

    float vst[2][4], ist[2][4];
    #pragma unroll
    for (int mt = 0; mt < 2; ++mt)
        #pragma unroll
        for (int r = 0; r < 4; ++r) { vst[mt][r] = 0.f; ist[mt][r] = 0.f; }

    const f32x4 zero4 = {0.f, 0.f, 0.f, 0.f};

    for (int t = 0; t < T_STEPS; ++t) {
        if (t > 0) __syncthreads();

        uint4 raw;
        if (t + 1 < T_STEPS)
            raw = *(const uint4*)(s0 + (size_t)((t+1)*BATCH + b)*4096 + tid*16);

        const char* curB = (const char*)(sIn + (t&1)*4096);

        f32x4 acch[2], accl[2];
        #pragma unroll
        for (int mt = 0; mt < 2; ++mt) { acch[mt] = zero4; accl[mt] = zero4; }

        #pragma unroll
        for (int kt = 0; kt < 7; ++kt) {
            #pragma unroll
            for (int mt = 0; mt < 2; ++mt) {
                f16x8 a = *(const f16x8*)(curB + addrA[mt][kt]);
                acch[mt] = __builtin_amdgcn_mfma_f32_16x16x32_f16(
                    a, bfrH[kt], acch[mt], 0, 0, 0);
                accl[mt] = __builtin_amdgcn_mfma_f32_16x16x32_f16(
                    a, bfrM[kt], accl[mt], 0, 0, 0);
            }
        }

        size_t rowoff = (size_t)(t*BATCH + b) * 6272;
        #pragma unroll
        for (int mt = 0; mt < 2; ++mt) {
            int posb = wm*32 + mt*16 + kg*4;
            int ocn = quad*16 + l15;
            unsigned char pk[4];
            #pragma unroll
            for (int r = 0; r < 4; ++r) {
                float inp = __fadd_rn(acch[mt][r], __fmul_rn(S2LO, accl[mt][r]));
                float z = lif_update(inp, vst[mt][r], ist[mt][r], 0.2f);
                int pos = posb + r;
                pk[r] = (pos <= 120 && z > 0.5f) ? (unsigned char)1 : (unsigned char)0;
            }
            if (ocn < 50 && posb < 121)
                *(uchar4*)(z1 + rowoff + ocn*124 + posb) = *(const uchar4*)&pk[0];
        }
        if (quad == 0 && tid < 72) z1[rowoff + 6200 + tid] = 0;

        if (t + 1 < T_STEPS) {
            unsigned short hv[16];
            #pragma unroll
            for (int w = 0; w < 4; ++w) {
                unsigned int u = ((const unsigned int*)&raw)[w];
                #pragma unroll
                for (int j = 0; j < 4; ++j)
                    hv[w*4+j] = f2h_bits((float)((u >> (8*j)) & 0xFFu));
            }
            unsigned short* dst = sIn + ((t+1)&1)*4096 + tid*16;
            *(f16x8*)dst       = *(const f16x8*)&hv[0];
            *(f16x8*)(dst + 8) = *(const f16x8*)&hv[8];
        }
    }
}

// ---------------------------------------------------------------------------
// fc1 GEMM, int8 3-plane, BK=128, 64x64 tile, 32 KB LDS -> 5 blocks/CU.
// Single 2560-block dispatch (160,8,2) = 10/CU = 2 clean residency waves.
// (R9/R11/R12-proven: ~103us, conflicts 0, Occupancy 35%.)
// ---------------------------------------------------------------------------
__global__ __launch_bounds__(256, 4) void k_gemm_fc1(
    const unsigned char* __restrict__ A,    // z1 [10240][6272] u8 spikes
    const signed char* __restrict__ Bq,     // [3][512][6272] i8 planes
    float* __restrict__ P)                  // [2][10240][512] fp32 partials
{
    __shared__ __align__(16) unsigned char As[64*128];    // 8 KB
    __shared__ __align__(16) unsigned char Bs[3*64*128];  // 24 KB

    const int tid  = threadIdx.x;
    const int lane = tid & 63;
    const int wv   = tid >> 6;
    const int wm   = wv & 1, wn = wv >> 1;        // 2 m-halves x 2 n-halves
    const int l15  = lane & 15, kg = lane >> 4;
    const int mbase = blockIdx.x * 64;
    const int nbase = blockIdx.y * 64;
    const int kz    = blockIdx.z;
    const int kb0   = kz * 3200;                  // 25*128
    const int kiters = 25 - kz;                   // 25 / 24

    float* Pz = P + (size_t)kz * 5242880;

    i32x4 acc[3][2][2];                           // plane, mt, nt
    #pragma unroll
    for (int p = 0; p < 3; ++p)
        #pragma unroll
        for (int mt = 0; mt < 2; ++mt)
            #pragma unroll
            for (int nt = 0; nt < 2; ++nt) acc[p][mt][nt] = (i32x4){0,0,0,0};

    const int rowS = tid >> 3;    // 0..31
    const int chk  = tid & 7;     // physical 16B chunk 0..7
    char* ldsA = (char*)As + (size_t)wv*1024;
    char* ldsB = (char*)Bs + (size_t)wv*1024;

    for (int ki = 0; ki < kiters; ++ki) {
        int kb = kb0 + ki * 128;
        #pragma unroll
        for (int c = 0; c < 2; ++c) {
            int rl = c*32 + rowS;
            llds16(A + (size_t)(mbase + rl)*6272 + kb + 16*(chk ^ (rl & 7)),
                   ldsA + c*4096);
        }
        #pragma unroll
        for (int p = 0; p < 3; ++p)
            #pragma unroll
            for (int c2 = 0; c2 < 2; ++c2) {
                int rl = c2*32 + rowS;
                llds16(Bq + (size_t)p*3211264 + (size_t)(nbase + rl)*6272
                          + kb + 16*(chk ^ (rl & 7)),
                       ldsB + (p*2 + c2)*4096);
            }
        __syncthreads();

        #pragma unroll
        for (int ks = 0; ks < 2; ++ks) {          // two K=64 halves
            i32x4 afv[2], bfv[3][2];
            #pragma unroll
            for (int nt = 0; nt < 2; ++nt) {
                int rb = wn*32 + nt*16 + l15;
                int off = rb*128 + 16*((ks*4 + kg) ^ (rb & 7));
                #pragma unroll
                for (int p = 0; p < 3; ++p)
                    bfv[p][nt] = *(const i32x4*)&Bs[p*8192 + off];
            }
            #pragma unroll
            for (int mt = 0; mt < 2; ++mt) {
                int ra = wm*32 + mt*16 + l15;
                afv[mt] = *(const i32x4*)&As[ra*128 + 16*((ks*4 + kg) ^ (ra & 7))];
            }
            #pragma unroll
            for (int p = 0; p < 3; ++p)
                #pragma unroll
                for (int mt = 0; mt < 2; ++mt)
                    #pragma unroll
                    for (int nt = 0; nt < 2; ++nt)
                        acc[p][mt][nt] = __builtin_amdgcn_mfma_i32_16x16x64_i8(
                            afv[mt], bfv[p][nt], acc[p][mt][nt], 0, 0, 0);
        }
        __syncthreads();
    }

    #pragma unroll
    for (int mt = 0; mt < 2; ++mt) {
        int m0 = mbase + wm*32 + mt*16 + kg*4;
        #pragma unroll
        for (int nt = 0; nt < 2; ++nt) {
            int n = nbase + wn*32 + nt*16 + l15;
            #pragma unroll
            for (int r = 0; r < 4; ++r) {
                float d = __fadd_rn(
                    __fadd_rn(__fmul_rn(16384.0f, (float)acc[2][mt][nt][r]),
                              __fmul_rn(128.0f,   (float)acc[1][mt][nt][r])),
                    (float)acc[0][mt][nt][r]);
                Pz[(size_t)(m0 + r)*512 + n] = __fmul_rn(WQ_S, d);
            }
        }
    }
}

// ---------------------------------------------------------------------------
// fc2 GEMM, PLANE-FUSED hi/lo fp16, 64x64 tile, K=512 (8 steps of BK=64).
// Grid (160,4)=640 blocks, 24 KB LDS -> 6 resident/CU: ALL co-resident.
// combine s = hi + 2^-12*lo in epilogue. (R10-R12-proven.)
// ---------------------------------------------------------------------------
__global__ __launch_bounds__(256, 6) void k_gemm_fc2(
    const unsigned short* __restrict__ A,     // z2 [10240][512] fp16
    const unsigned short* __restrict__ B,     // W2 hi | lo (+131072)
    float* __restrict__ C)                    // c3 [10240][256] fp32
{
    __shared__ __align__(16) unsigned short As[64*64];   // 8 KB
    __shared__ __align__(16) unsigned short Bh[64*64];   // 8 KB
    __shared__ __align__(16) unsigned short Bl[64*64];   // 8 KB

    const int tid  = threadIdx.x;
    const int lane = tid & 63;
    const int wv   = tid >> 6;
    const int wm   = wv & 1, wn = wv >> 1;
    const int l15  = lane & 15, kg = lane >> 4;
    const int mbase = blockIdx.x * 64;
    const int nbase = blockIdx.y * 64;
    const unsigned short* Blo = B + 131072;

    const f32x4 zero4 = {0.f, 0.f, 0.f, 0.f};
    f32x4 acch[2][2], accl[2][2];
    #pragma unroll
    for (int mt = 0; mt < 2; ++mt)
        #pragma unroll
        for (int nt = 0; nt < 2; ++nt) { acch[mt][nt] = zero4; accl[mt][nt] = zero4; }

    const int rowS = tid >> 3;    // 0..31
    const int chk  = tid & 7;     // physical 16B chunk (8 f16)
    char* ldsA = (char*)As + (size_t)wv*1024;
    char* ldsH = (char*)Bh + (size_t)wv*1024;
    char* ldsL = (char*)Bl + (size_t)wv*1024;

    for (int ki = 0; ki < 8; ++ki) {
        int kb = ki * 64;
        #pragma unroll
        for (int c = 0; c < 2; ++c) {
            int rl = c*32 + rowS;
            int sw = (chk ^ (rl & 7)) * 8;            // elems
            llds16(A   + (size_t)(mbase + rl)*512 + kb + sw, ldsA + c*4096);
            llds16(B   + (size_t)(nbase + rl)*512 + kb + sw, ldsH + c*4096);
            llds16(Blo + (size_t)(nbase + rl)*512 + kb + sw, ldsL + c*4096);
        }
        __syncthreads();
        #pragma unroll
        for (int kt = 0; kt < 2; ++kt) {
            f16x8 bh[2], bl[2], afv[2];
            #pragma unroll
            for (int nt = 0; nt < 2; ++nt) {
                int rb = wn*32 + nt*16 + l15;
                int ch = ((kt*4 + kg) ^ (rb & 7)) * 8;
                bh[nt] = *(const f16x8*)&Bh[rb*64 + ch];
                bl[nt] = *(const f16x8*)&Bl[rb*64 + ch];
            }
            #pragma unroll
            for (int mt = 0; mt < 2; ++mt) {
                int ra = wm*32 + mt*16 + l15;
                int ch = ((kt*4 + kg) ^ (ra & 7)) * 8;
                afv[mt] = *(const f16x8*)&As[ra*64 + ch];
            }
            #pragma unroll
            for (int mt = 0; mt < 2; ++mt)
                #pragma unroll
                for (int nt = 0; nt < 2; ++nt) {
                    acch[mt][nt] = __builtin_amdgcn_mfma_f32_16x16x32_f16(
                        afv[mt], bh[nt], acch[mt][nt], 0, 0, 0);
                    accl[mt][nt] = __builtin_amdgcn_mfma_f32_16x16x32_f16(
                        afv[mt], bl[nt], accl[mt][nt], 0, 0, 0);
                }
        }
        __syncthreads();
    }

    #pragma unroll
    for (int mt = 0; mt < 2; ++mt) {
        int m0 = mbase + wm*32 + mt*16 + kg*4;
        #pragma unroll
        for (int nt = 0; nt < 2; ++nt) {
            int n = nbase + wn*32 + nt*16 + l15;
            #pragma unroll
            for (int r = 0; r < 4; ++r) {
                float s = __fadd_rn(acch[mt][nt][r], __fmul_rn(S2LO, accl[mt][nt][r]));
                C[(size_t)(m0 + r)*256 + n] = s;
            }
        }
    }
}

// LIF scan over t, planar pair (c0[idx], c0[idx+pstride]).
// Grid (nsplit, 256): b = blockIdx.y, n = blockIdx.x*blockDim.x + tid.
// 4-deep software pipeline (static regs).
__global__ void k_lif_scan(
    const float* __restrict__ c0, size_t pstride,
    unsigned short* __restrict__ zout,
    int ld, int nvalid, float vth, float pscale)
{
    int b = blockIdx.y;
    int n = blockIdx.x*blockDim.x + threadIdx.x;
    float v = 0.f, cur = 0.f;
    const float* sx = c0 + (size_t)b*ld + n;
    const float* sy = sx + pstride;
    const size_t step = (size_t)BATCH*ld;
    float x0 = sx[0],      y0 = sy[0];
    float x1 = sx[step],   y1 = sy[step];
    float x2 = sx[2*step], y2 = sy[2*step];
    float x3 = sx[3*step], y3 = sy[3*step];

    #define LIF_SUB(J, XV, YV)                                                \
        {                                                                     \
            float s = __fadd_rn(XV, __fmul_rn(pscale, YV));                   \
            float z = lif_update(s, v, cur, vth);                             \
            zout[(size_t)((t+J)*BATCH + b)*ld + n] =                          \
                (n < nvalid && z > 0.5f) ? (unsigned short)0x3C00             \
                                         : (unsigned short)0;                 \
            if (t + J + 4 < T_STEPS) {                                        \
                XV = sx[(size_t)(t + J + 4)*step];                            \
                YV = sy[(size_t)(t + J + 4)*step];                            \
            }                                                                 \
        }

    for (int t = 0; t < T_STEPS; t += 4) {
        LIF_SUB(0, x0, y0);
        LIF_SUB(1, x1, y1);
        LIF_SUB(2, x2, y2);
        LIF_SUB(3, x3, y3);
    }
    #undef LIF_SUB
}

// ---------------------------------------------------------------------------
// Fused scan2 (LIF vth=0.05, single combined input) + fc_out GEMM + LI scan.
// One block per sample b. c3 is the pre-combined fp32 stream from fc2.
// ---------------------------------------------------------------------------
__global__ __launch_bounds__(256) void k_sc2_fcout_li(
    const float* __restrict__ c3,                   // [10240][256] fp32
    const float* __restrict__ wfo,                  // [10, 200] fp32
    float* __restrict__ out)                        // [T, B, 10] fp32
{
    const int b   = blockIdx.x;
    const int tid = threadIdx.x;
    __shared__ __align__(16) float wfoL[2000];          // [10][200]
    __shared__ unsigned char z3L[T_STEPS*200];          // 8 KB
    __shared__ float sL[400];                           // [40][10]

    for (int i = tid; i < 2000; i += 256) wfoL[i] = wfo[i];

    if (tid < 200) {
        const float* sx = c3 + (size_t)b*256 + tid;
        const size_t step = (size_t)BATCH*256;
        float v = 0.f, cur = 0.f;
        float x0 = sx[0], x1 = sx[step], x2 = sx[2*step], x3 = sx[3*step];

        #define SC2_SUB(J, XV)                                                \
            {                                                                 \
                float z = lif_update(XV, v, cur, 0.05f);                      \
                z3L[(t+J)*200 + tid] = (z > 0.5f) ? 1 : 0;                    \
                if (t + J + 4 < T_STEPS)                                      \
                    XV = sx[(size_t)(t + J + 4)*step];                        \
            }

        for (int t = 0; t < T_STEPS; t += 4) {
            SC2_SUB(0, x0);
            SC2_SUB(1, x1);
            SC2_SUB(2, x2);
            SC2_SUB(3, x3);
        }
        #undef SC2_SUB
    }
    __syncthreads();

    #pragma unroll
    for (int rep = 0; rep < 2; ++rep) {
        int task = tid + rep*256;
        if (task < 400) {
            int t = task / 10, n = task - t*10;
            float acc = 0.f;
            for (int k = 0; k < 200; k += 4) {
                uchar4 zb = *(const uchar4*)&z3L[t*200 + k];
                float4 wv = *(const float4*)&wfoL[n*200 + k];
                acc = __fadd_rn(acc, zb.x ? wv.x : 0.f);
                acc = __fadd_rn(acc, zb.y ? wv.y : 0.f);
                acc = __fadd_rn(acc, zb.z ? wv.z : 0.f);
                acc = __fadd_rn(acc, zb.w ? wv.w : 0.f);
            }
            sL[t*10 + n] = acc;
        }
    }
    __syncthreads();

    if (tid < 10) {
        float vo = 0.f, io = 0.f;
        for (int t = 0; t < T_STEPS; ++t) {
            float vd = __fadd_rn(vo, __fmul_rn(0.1f, __fsub_rn(io, vo)));
            out[((size_t)(t*BATCH + b))*10 + tid] = vd;
            io = __fadd_rn(__fmul_rn(0.8f, io), sL[t*10 + tid]);
            vo = vd;
        }
    }
}

extern "C" void kernel_launch(void* const* d_in, const int* in_sizes, int n_in,
                              void* d_out, int out_size, void* d_ws, size_t ws_size,
                              hipStream_t stream) {
    (void)in_sizes; (void)n_in; (void)out_size; (void)ws_size;
    const float* x   = (const float*)d_in[0];
    const float* w1  = (const float*)d_in[1];
    const float* w2  = (const float*)d_in[2];
    const float* wf1 = (const float*)d_in[3];
    const float* wf2 = (const float*)d_in[4];
    const float* wfo = (const float*)d_in[5];
    char* ws = (char*)d_ws;

    // ---- workspace layout (peak 126.5 MB < 208.4 MB proven writable) ----
    // z1  u8 [0, 64,225,280)            10240 x 6272
    // s0  u8 [64,225,280, 106,168,320)  10240 x 4096 (live through conv2)
    // c2p fp32 [74,383,360, 116,326,400) [2][10240][512] (overlays dead s0,
    //        written by fc1 after conv2 completes)
    // W1q i8 [116,326,400, 125,960,192)  3 planes x 3,211,264 (OWN region:
    //        pack fused into conv2 runs concurrently with live s0 reads)
    // W2  fp16 [125,960,192, 126,484,480)
    // low region (z1 dead after fc1): z2 [0, 10,485,760) ;
    //   c3 [10,485,760, 20,971,520) [10240][256] fp32
    unsigned char*  z1    = (unsigned char*)(ws);
    unsigned char*  s0    = (unsigned char*)(ws + 64225280);
    float*          c2p   = (float*)(ws + 74383360);
    signed char*    W1q   = (signed char*)(ws + 116326400);
    unsigned short* W2hi  = (unsigned short*)(ws + 125960192);
    unsigned short* z2    = (unsigned short*)(ws);
    float*          c3    = (float*)(ws + 10485760);

    k_conv1<<<dim3(8, 256), 512, 0, stream>>>(x, w1, s0);
    // conv2 (blocks 0..1023, 4/CU resident) + pack (blocks 1024..1279,
    // 1/CU, co-resident as the 5th block -> runs concurrently)
    k_conv2<<<1280, 256, 0, stream>>>(s0, w2, z1, wf1, wf2, W1q, W2hi);

    // fc1: single balanced 2560-block dispatch (5 blocks/CU, 2 waves)
    k_gemm_fc1<<<dim3(160, 8, 2), 256, 0, stream>>>(z1, W1q, c2p);
    k_lif_scan<<<dim3(2, 256), 256, 0, stream>>>(c2p, (size_t)5242880, z2, 512, 500, 0.1f, 1.0f);
    k_gemm_fc2<<<dim3(160, 4), 256, 0, stream>>>(z2, W2hi, c3);
    k_sc2_fcout_li<<<256, 256, 0, stream>>>(c3, wfo, (float*)d_out);
}

// Round 14
// 351.786 us; speedup vs baseline: 1.0319x; 1.0319x over previous
//
#include <hip/hip_runtime.h>
#include <hip/hip_bf16.h>

typedef _Float16 f16x8 __attribute__((ext_vector_type(8)));
typedef float f32x4  __attribute__((ext_vector_type(4)));
typedef int   i32x4  __attribute__((ext_vector_type(4)));
typedef unsigned short u16x4 __attribute__((ext_vector_type(4)));

#define T_STEPS 40
#define BATCH   256
#define S2LO    0.000244140625f   // 2^-12, exact
// fc1 int8 3-plane quantization: w ~= WQ_S*(q2*16384 + q1*128 + q0)
#define WQ_INV  (2080768.0f/0.103f)   // 1/WQ_S ; 2080768 = 127*16384
#define WQ_S    (0.103f/2080768.0f)

__device__ __forceinline__ unsigned short f2h_bits(float f) {
    union { _Float16 h; unsigned short u; } c; c.h = (_Float16)f; return c.u;
}

// norse LIF step, pinned to mul-then-add fp32 order.
__device__ __forceinline__ float lif_update(float inp, float& v, float& i, float vth) {
    float vd = __fadd_rn(v, __fmul_rn(0.1f, __fsub_rn(i, v)));
    float id = __fmul_rn(0.8f, i);
    float z  = (vd > vth) ? 1.0f : 0.0f;
    v = (vd > vth) ? 0.0f : vd;
    i = __fadd_rn(id, inp);
    return z;
}

__device__ __forceinline__ void llds16(const void* g, void* l) {
    __builtin_amdgcn_global_load_lds(
        (const __attribute__((address_space(1))) unsigned int*)g,
        (__attribute__((address_space(3))) unsigned int*)l, 16, 0, 0);
}

// ---------------------------------------------------------------------------
// Kernel 1 (v7, R11-proven): conv1 + LIF0 + 2x2 avgpool. Row-range staging
// (<=8 of 28 rows per block), full-line wave stores, quad-buffered 2-deep
// register pipe.
// ---------------------------------------------------------------------------
__global__ __launch_bounds__(512) void k_conv1(
    const float* __restrict__ x,             // [T,B,784] fp32
    const float* __restrict__ w1,            // [20,1,3,3] fp32
    unsigned char* __restrict__ s0)          // [T,B,4096] u8
{
    const int b    = blockIdx.y;
    const int tid  = threadIdx.x;
    const int cell = blockIdx.x*512 + tid;   // 0..4095 == byte offset in row
    const int pos  = cell / 24;              // 0..170
    const int oc   = cell - pos*24;          // 0..23
    const bool active = (pos < 169) && (oc < 20);
    const int pr   = pos / 13, q = pos - pr*13;
    const int c0   = 2*q;

    // block-uniform staged row range
    const int p0    = (blockIdx.x*512) / 24;
    const int pmaxv = min((blockIdx.x*512 + 511) / 24, 168);
    const int rlo   = 2*(p0/13);                          // first row staged
    const int rhi   = min(2*(pmaxv/13) + 3, 27);          // last row staged
    const int nf4   = (rhi - rlo + 1) * 7;                // float4s (<=56)
    const int rloc  = 2*pr - rlo;                         // local row base

    __shared__ __align__(16) float xl[4][224];
    const bool stager = tid < nf4;

    float wr[9];
    if (active) {
        #pragma unroll
        for (int j = 0; j < 9; ++j) wr[j] = w1[oc*9 + j];
    }
    float vs[2][2], is[2][2];
    #pragma unroll
    for (int dr = 0; dr < 2; ++dr)
        #pragma unroll
        for (int dc = 0; dc < 2; ++dc) { vs[dr][dc] = 0.f; is[dr][dc] = 0.f; }

    float4 pA, pB;
    if (stager) {
        const float* xr = x + (size_t)b*784 + rlo*28;
        *(float4*)&xl[0][tid*4] = ((const float4*)(xr + 0*BATCH*784))[tid];
        *(float4*)&xl[1][tid*4] = ((const float4*)(xr + 1ull*BATCH*784))[tid];
        pA = ((const float4*)(xr + 2ull*BATCH*784))[tid];
        pB = ((const float4*)(xr + 3ull*BATCH*784))[tid];
    }

    for (int t = 0; t < T_STEPS; ++t) {
        __syncthreads();   // buf[t&3] ready; buf[(t+2)&3] consumers done
        if (stager) {
            if (t + 2 < T_STEPS) *(float4*)&xl[(t+2)&3][tid*4] = pA;
            pA = pB;
            if (t + 4 < T_STEPS)
                pB = ((const float4*)(x + (size_t)((t+4)*BATCH + b)*784 + rlo*28))[tid];
        }
        const float* xc = xl[t&3];
        size_t base = (size_t)(t*BATCH + b) * 4096;

        unsigned char outb = 0;
        if (active) {
            float tle[4][4];
            #pragma unroll
            for (int r = 0; r < 4; ++r) {
                float2 t01 = *(const float2*)&xc[(rloc + r)*28 + c0];
                float2 t23 = *(const float2*)&xc[(rloc + r)*28 + c0 + 2];
                tle[r][0] = t01.x; tle[r][1] = t01.y;
                tle[r][2] = t23.x; tle[r][3] = t23.y;
            }
            int zsum = 0;
            #pragma unroll
            for (int dr = 0; dr < 2; ++dr)
                #pragma unroll
                for (int dc = 0; dc < 2; ++dc) {
                    float acc = 0.f;
                    #pragma unroll
                    for (int kr = 0; kr < 3; ++kr)
                        #pragma unroll
                        for (int kc = 0; kc < 3; ++kc)
                            acc += tle[dr+kr][dc+kc] * wr[kr*3+kc];
                    float z = lif_update(acc, vs[dr][dc], is[dr][dc], 0.2f);
                    zsum += (z > 0.5f) ? 1 : 0;
                }
            outb = (unsigned char)zsum;
        }
        s0[base + cell] = outb;   // wave = 64 consecutive bytes = 1 full line
    }
}

// ---------------------------------------------------------------------------
// Kernel 2 (v3, R12-proven): conv2 via fp16 MFMA, 4 blocks/sample.
// Quad-major mapping (b = bid&255, quad = bid>>8) -> s0 row re-read is
// L2-served; w2m fragments hoisted to registers (-33% LDS traffic).
// Weights carry the exact x0.25 pool scale. z1: U8 SPIKES {0,1}, row stride
// 6272 (=49*128), [oc50][pos124] + 72B pad.
// ---------------------------------------------------------------------------
__global__ __launch_bounds__(256, 4) void k_conv2(
    const unsigned char* __restrict__ s0,    // [T,B,4096] u8
    const float* __restrict__ w2,            // [50,20,3,3] fp32
    unsigned char* __restrict__ z1)          // [T,B,6272] u8 spikes
{
    const int b    = blockIdx.x & 255;       // quad-major
    const int quad = blockIdx.x >> 8;
    const int tid  = threadIdx.x;
    const int wv   = tid >> 6;
    const int lane = tid & 63;
    const int l15  = lane & 15;
    const int kg   = lane >> 4;
    const int wm   = wv;           // 4 m-waves x 32 pos

    __shared__ __align__(16) unsigned short w2h[16*232];
    __shared__ __align__(16) unsigned short w2m[16*232];
    __shared__ __align__(16) unsigned short sIn[2*4096];   // fp16 double buffer

    for (int s = tid; s < 16*232; s += 256) {
        int ocw = s / 232, kk = s % 232;
        int g = kk / 24, ic = kk % 24;
        int oc = quad*16 + ocw;
        float val = 0.f;
        if (oc < 50 && g < 9 && ic < 20) val = 0.25f * w2[(oc*20 + ic)*9 + g];
        _Float16 h = (_Float16)val;
        float r1 = (val - (float)h) * 4096.0f;
        union { _Float16 h; unsigned short u; } ch, cm;
        ch.h = h; cm.h = (_Float16)r1;
        w2h[s] = ch.u;
        w2m[s] = cm.u;
    }

    f16x8 bfrH[7], bfrM[7];
    int addrA[2][7];
    #pragma unroll
    for (int mt = 0; mt < 2; ++mt) {
        int pos = wm*32 + mt*16 + l15;
        #pragma unroll
        for (int kt = 0; kt < 7; ++kt) {
            int k = kt*32 + kg*8;
            int g = k / 24, o = k - g*24;
            if (pos <= 120 && g <= 8) {
                int in_idx = pos + 2*(pos/11) + 13*(g/3) + (g % 3);
                addrA[mt][kt] = in_idx*48 + o*2;
            } else addrA[mt][kt] = 8128;   // elem 4064: zeroed tail
        }
    }

    // stage t=0 (u8 -> f16, exact small ints)
    {
        const unsigned char* srow = s0 + (size_t)(0*BATCH + b)*4096;
        uint4 raw = *(const uint4*)(srow + tid*16);
        unsigned short hv[16];
        #pragma unroll
        for (int w = 0; w < 4; ++w) {
            unsigned int u = ((const unsigned int*)&raw)[w];
            #pragma unroll
            for (int j = 0; j < 4; ++j)
                hv[w*4+j] = f2h_bits((float)((u >> (8*j)) & 0xFFu));
        }
        unsigned short* dst = sIn + tid*16;
        *(f16x8*)dst       = *(const f16x8*)&hv[0];
        *(f16x8*)(dst + 8) = *(const f16x8*)&hv[8];
    }
    __syncthreads();

    #pragma unroll
    for (int kt = 0; kt < 7; ++kt) {
        bfrH[kt] = *(const f16x8*)&w2h[l15*232 + kt*32 + kg*8];
        bfrM[kt] = *(const f16x8*)&w2m[l15*232 + kt*32 + kg*8];   // hoist
    }

    float vst[2][4], ist[2][4];
    #pragma unroll
    for (int mt = 0; mt < 2; ++mt)
        #pragma unroll
        for (int r = 0; r < 4; ++r) { vst[mt][r] = 0.f; ist[mt][r] = 0.f; }

    const f32x4 zero4 = {0.f, 0.f, 0.f, 0.f};

    for (int t = 0; t < T_STEPS; ++t) {
        if (t > 0) __syncthreads();

        uint4 raw;
        if (t + 1 < T_STEPS)
            raw = *(const uint4*)(s0 + (size_t)((t+1)*BATCH + b)*4096 + tid*16);

        const char* curB = (const char*)(sIn + (t&1)*4096);

        f32x4 acch[2], accl[2];
        #pragma unroll
        for (int mt = 0; mt < 2; ++mt) { acch[mt] = zero4; accl[mt] = zero4; }

        #pragma unroll
        for (int kt = 0; kt < 7; ++kt) {
            #pragma unroll
            for (int mt = 0; mt < 2; ++mt) {
                f16x8 a = *(const f16x8*)(curB + addrA[mt][kt]);
                acch[mt] = __builtin_amdgcn_mfma_f32_16x16x32_f16(
                    a, bfrH[kt], acch[mt], 0, 0, 0);
                accl[mt] = __builtin_amdgcn_mfma_f32_16x16x32_f16(
                    a, bfrM[kt], accl[mt], 0, 0, 0);
            }
        }

        size_t rowoff = (size_t)(t*BATCH + b) * 6272;
        #pragma unroll
        for (int mt = 0; mt < 2; ++mt) {
            int posb = wm*32 + mt*16 + kg*4;
            int ocn = quad*16 + l15;
            unsigned char pk[4];
            #pragma unroll
            for (int r = 0; r < 4; ++r) {
                float inp = __fadd_rn(acch[mt][r], __fmul_rn(S2LO, accl[mt][r]));
                float z = lif_update(inp, vst[mt][r], ist[mt][r], 0.2f);
                int pos = posb + r;
                pk[r] = (pos <= 120 && z > 0.5f) ? (unsigned char)1 : (unsigned char)0;
            }
            if (ocn < 50 && posb < 121)
                *(uchar4*)(z1 + rowoff + ocn*124 + posb) = *(const uchar4*)&pk[0];
        }
        if (quad == 0 && tid < 72) z1[rowoff + 6200 + tid] = 0;

        if (t + 1 < T_STEPS) {
            unsigned short hv[16];
            #pragma unroll
            for (int w = 0; w < 4; ++w) {
                unsigned int u = ((const unsigned int*)&raw)[w];
                #pragma unroll
                for (int j = 0; j < 4; ++j)
                    hv[w*4+j] = f2h_bits((float)((u >> (8*j)) & 0xFFu));
            }
            unsigned short* dst = sIn + ((t+1)&1)*4096 + tid*16;
            *(f16x8*)dst       = *(const f16x8*)&hv[0];
            *(f16x8*)(dst + 8) = *(const f16x8*)&hv[8];
        }
    }
}

// ---------------------------------------------------------------------------
// fc1 GEMM, int8 3-plane, BK=128, 64x64 tile, 32 KB LDS -> 5 blocks/CU.
// Single 2560-block dispatch (160,8,2) = 10/CU = 2 clean residency waves.
// (R9/R11/R12-proven: ~103us, conflicts 0, Occupancy 35%.)
// ---------------------------------------------------------------------------
__global__ __launch_bounds__(256, 4) void k_gemm_fc1(
    const unsigned char* __restrict__ A,    // z1 [10240][6272] u8 spikes
    const signed char* __restrict__ Bq,     // [3][512][6272] i8 planes
    float* __restrict__ P)                  // [2][10240][512] fp32 partials
{
    __shared__ __align__(16) unsigned char As[64*128];    // 8 KB
    __shared__ __align__(16) unsigned char Bs[3*64*128];  // 24 KB

    const int tid  = threadIdx.x;
    const int lane = tid & 63;
    const int wv   = tid >> 6;
    const int wm   = wv & 1, wn = wv >> 1;        // 2 m-halves x 2 n-halves
    const int l15  = lane & 15, kg = lane >> 4;
    const int mbase = blockIdx.x * 64;
    const int nbase = blockIdx.y * 64;
    const int kz    = blockIdx.z;
    const int kb0   = kz * 3200;                  // 25*128
    const int kiters = 25 - kz;                   // 25 / 24

    float* Pz = P + (size_t)kz * 5242880;

    i32x4 acc[3][2][2];                           // plane, mt, nt
    #pragma unroll
    for (int p = 0; p < 3; ++p)
        #pragma unroll
        for (int mt = 0; mt < 2; ++mt)
            #pragma unroll
            for (int nt = 0; nt < 2; ++nt) acc[p][mt][nt] = (i32x4){0,0,0,0};

    const int rowS = tid >> 3;    // 0..31
    const int chk  = tid & 7;     // physical 16B chunk 0..7
    char* ldsA = (char*)As + (size_t)wv*1024;
    char* ldsB = (char*)Bs + (size_t)wv*1024;

    for (int ki = 0; ki < kiters; ++ki) {
        int kb = kb0 + ki * 128;
        #pragma unroll
        for (int c = 0; c < 2; ++c) {
            int rl = c*32 + rowS;
            llds16(A + (size_t)(mbase + rl)*6272 + kb + 16*(chk ^ (rl & 7)),
                   ldsA + c*4096);
        }
        #pragma unroll
        for (int p = 0; p < 3; ++p)
            #pragma unroll
            for (int c2 = 0; c2 < 2; ++c2) {
                int rl = c2*32 + rowS;
                llds16(Bq + (size_t)p*3211264 + (size_t)(nbase + rl)*6272
                          + kb + 16*(chk ^ (rl & 7)),
                       ldsB + (p*2 + c2)*4096);
            }
        __syncthreads();

        #pragma unroll
        for (int ks = 0; ks < 2; ++ks) {          // two K=64 halves
            i32x4 afv[2], bfv[3][2];
            #pragma unroll
            for (int nt = 0; nt < 2; ++nt) {
                int rb = wn*32 + nt*16 + l15;
                int off = rb*128 + 16*((ks*4 + kg) ^ (rb & 7));
                #pragma unroll
                for (int p = 0; p < 3; ++p)
                    bfv[p][nt] = *(const i32x4*)&Bs[p*8192 + off];
            }
            #pragma unroll
            for (int mt = 0; mt < 2; ++mt) {
                int ra = wm*32 + mt*16 + l15;
                afv[mt] = *(const i32x4*)&As[ra*128 + 16*((ks*4 + kg) ^ (ra & 7))];
            }
            #pragma unroll
            for (int p = 0; p < 3; ++p)
                #pragma unroll
                for (int mt = 0; mt < 2; ++mt)
                    #pragma unroll
                    for (int nt = 0; nt < 2; ++nt)
                        acc[p][mt][nt] = __builtin_amdgcn_mfma_i32_16x16x64_i8(
                            afv[mt], bfv[p][nt], acc[p][mt][nt], 0, 0, 0);
        }
        __syncthreads();
    }

    #pragma unroll
    for (int mt = 0; mt < 2; ++mt) {
        int m0 = mbase + wm*32 + mt*16 + kg*4;
        #pragma unroll
        for (int nt = 0; nt < 2; ++nt) {
            int n = nbase + wn*32 + nt*16 + l15;
            #pragma unroll
            for (int r = 0; r < 4; ++r) {
                float d = __fadd_rn(
                    __fadd_rn(__fmul_rn(16384.0f, (float)acc[2][mt][nt][r]),
                              __fmul_rn(128.0f,   (float)acc[1][mt][nt][r])),
                    (float)acc[0][mt][nt][r]);
                Pz[(size_t)(m0 + r)*512 + n] = __fmul_rn(WQ_S, d);
            }
        }
    }
}

// ---------------------------------------------------------------------------
// fc2 GEMM, PLANE-FUSED hi/lo fp16, 64x64 tile, K=512 (8 steps of BK=64).
// Grid (160,4)=640 blocks, 24 KB LDS -> 6 resident/CU: ALL co-resident.
// combine s = hi + 2^-12*lo in epilogue. (R10-R12-proven.)
// ---------------------------------------------------------------------------
__global__ __launch_bounds__(256, 6) void k_gemm_fc2(
    const unsigned short* __restrict__ A,     // z2 [10240][512] fp16
    const unsigned short* __restrict__ B,     // W2 hi | lo (+131072)
    float* __restrict__ C)                    // c3 [10240][256] fp32
{
    __shared__ __align__(16) unsigned short As[64*64];   // 8 KB
    __shared__ __align__(16) unsigned short Bh[64*64];   // 8 KB
    __shared__ __align__(16) unsigned short Bl[64*64];   // 8 KB

    const int tid  = threadIdx.x;
    const int lane = tid & 63;
    const int wv   = tid >> 6;
    const int wm   = wv & 1, wn = wv >> 1;
    const int l15  = lane & 15, kg = lane >> 4;
    const int mbase = blockIdx.x * 64;
    const int nbase = blockIdx.y * 64;
    const unsigned short* Blo = B + 131072;

    const f32x4 zero4 = {0.f, 0.f, 0.f, 0.f};
    f32x4 acch[2][2], accl[2][2];
    #pragma unroll
    for (int mt = 0; mt < 2; ++mt)
        #pragma unroll
        for (int nt = 0; nt < 2; ++nt) { acch[mt][nt] = zero4; accl[mt][nt] = zero4; }

    const int rowS = tid >> 3;    // 0..31
    const int chk  = tid & 7;     // physical 16B chunk (8 f16)
    char* ldsA = (char*)As + (size_t)wv*1024;
    char* ldsH = (char*)Bh + (size_t)wv*1024;
    char* ldsL = (char*)Bl + (size_t)wv*1024;

    for (int ki = 0; ki < 8; ++ki) {
        int kb = ki * 64;
        #pragma unroll
        for (int c = 0; c < 2; ++c) {
            int rl = c*32 + rowS;
            int sw = (chk ^ (rl & 7)) * 8;            // elems
            llds16(A   + (size_t)(mbase + rl)*512 + kb + sw, ldsA + c*4096);
            llds16(B   + (size_t)(nbase + rl)*512 + kb + sw, ldsH + c*4096);
            llds16(Blo + (size_t)(nbase + rl)*512 + kb + sw, ldsL + c*4096);
        }
        __syncthreads();
        #pragma unroll
        for (int kt = 0; kt < 2; ++kt) {
            f16x8 bh[2], bl[2], afv[2];
            #pragma unroll
            for (int nt = 0; nt < 2; ++nt) {
                int rb = wn*32 + nt*16 + l15;
                int ch = ((kt*4 + kg) ^ (rb & 7)) * 8;
                bh[nt] = *(const f16x8*)&Bh[rb*64 + ch];
                bl[nt] = *(const f16x8*)&Bl[rb*64 + ch];
            }
            #pragma unroll
            for (int mt = 0; mt < 2; ++mt) {
                int ra = wm*32 + mt*16 + l15;
                int ch = ((kt*4 + kg) ^ (ra & 7)) * 8;
                afv[mt] = *(const f16x8*)&As[ra*64 + ch];
            }
            #pragma unroll
            for (int mt = 0; mt < 2; ++mt)
                #pragma unroll
                for (int nt = 0; nt < 2; ++nt) {
                    acch[mt][nt] = __builtin_amdgcn_mfma_f32_16x16x32_f16(
                        afv[mt], bh[nt], acch[mt][nt], 0, 0, 0);
                    accl[mt][nt] = __builtin_amdgcn_mfma_f32_16x16x32_f16(
                        afv[mt], bl[nt], accl[mt][nt], 0, 0, 0);
                }
        }
        __syncthreads();
    }

    #pragma unroll
    for (int mt = 0; mt < 2; ++mt) {
        int m0 = mbase + wm*32 + mt*16 + kg*4;
        #pragma unroll
        for (int nt = 0; nt < 2; ++nt) {
            int n = nbase + wn*32 + nt*16 + l15;
            #pragma unroll
            for (int r = 0; r < 4; ++r) {
                float s = __fadd_rn(acch[mt][nt][r], __fmul_rn(S2LO, accl[mt][nt][r]));
                C[(size_t)(m0 + r)*256 + n] = s;
            }
        }
    }
}

// ---------------------------------------------------------------------------
// Weight pack (R9-proven): fc1 -> 3 i8 planes (Kp=6272); fc2 -> fp16 hi/lo.
// ---------------------------------------------------------------------------
__global__ void k_pack_all(
    const float* __restrict__ wf1, const float* __restrict__ wf2,
    signed char* __restrict__ W1, unsigned short* __restrict__ W2)
{
    int idx = blockIdx.x*256 + threadIdx.x;
    if (idx < 3211264) {                       // 512*6272
        int n = idx / 6272, k = idx - n*6272;
        int oc = k / 124, pos = k - oc*124;
        float v = (n < 500 && oc < 50 && pos < 121) ? wf1[n*6050 + oc*121 + pos] : 0.f;
        float a = v * WQ_INV;
        int q2 = __float2int_rn(a * (1.0f/16384.0f));
        q2 = q2 < -127 ? -127 : (q2 > 127 ? 127 : q2);
        float r1 = a - (float)q2 * 16384.0f;
        int q1 = __float2int_rn(r1 * (1.0f/128.0f));
        q1 = q1 < -127 ? -127 : (q1 > 127 ? 127 : q1);
        float r0 = r1 - (float)q1 * 128.0f;
        int q0 = __float2int_rn(r0);
        q0 = q0 < -127 ? -127 : (q0 > 127 ? 127 : q0);
        W1[idx]             = (signed char)q0;
        W1[idx + 3211264]   = (signed char)q1;
        W1[idx + 2*3211264] = (signed char)q2;
        return;
    }
    if (idx < 3211264 + 131072) {
        int i2 = idx - 3211264;
        int n = i2 >> 9, k = i2 & 511;
        float v = (n < 200 && k < 500) ? wf2[n*500 + k] : 0.f;
        _Float16 h = (_Float16)v;
        float r1 = (v - (float)h) * 4096.0f;
        union { _Float16 h; unsigned short u; } ch, cl;
        ch.h = h; cl.h = (_Float16)r1;
        W2[i2] = ch.u;
        W2[i2 + 131072] = cl.u;
    }
}

// LIF scan over t, planar pair (c0[idx], c0[idx+pstride]).
// Grid (nsplit, 256): b = blockIdx.y, n = blockIdx.x*blockDim.x + tid.
// 4-deep software pipeline (static regs).
__global__ void k_lif_scan(
    const float* __restrict__ c0, size_t pstride,
    unsigned short* __restrict__ zout,
    int ld, int nvalid, float vth, float pscale)
{
    int b = blockIdx.y;
    int n = blockIdx.x*blockDim.x + threadIdx.x;
    float v = 0.f, cur = 0.f;
    const float* sx = c0 + (size_t)b*ld + n;
    const float* sy = sx + pstride;
    const size_t step = (size_t)BATCH*ld;
    float x0 = sx[0],      y0 = sy[0];
    float x1 = sx[step],   y1 = sy[step];
    float x2 = sx[2*step], y2 = sy[2*step];
    float x3 = sx[3*step], y3 = sy[3*step];

    #define LIF_SUB(J, XV, YV)                                                \
        {                                                                     \
            float s = __fadd_rn(XV, __fmul_rn(pscale, YV));                   \
            float z = lif_update(s, v, cur, vth);                             \
            zout[(size_t)((t+J)*BATCH + b)*ld + n] =                          \
                (n < nvalid && z > 0.5f) ? (unsigned short)0x3C00             \
                                         : (unsigned short)0;                 \
            if (t + J + 4 < T_STEPS) {                                        \
                XV = sx[(size_t)(t + J + 4)*step];                            \
                YV = sy[(size_t)(t + J + 4)*step];                            \
            }                                                                 \
        }

    for (int t = 0; t < T_STEPS; t += 4) {
        LIF_SUB(0, x0, y0);
        LIF_SUB(1, x1, y1);
        LIF_SUB(2, x2, y2);
        LIF_SUB(3, x3, y3);
    }
    #undef LIF_SUB
}

// ---------------------------------------------------------------------------
// Fused scan2 (LIF vth=0.05, single combined input) + fc_out GEMM + LI scan.
// One block per sample b. c3 is the pre-combined fp32 stream from fc2.
// ---------------------------------------------------------------------------
__global__ __launch_bounds__(256) void k_sc2_fcout_li(
    const float* __restrict__ c3,                   // [10240][256] fp32
    const float* __restrict__ wfo,                  // [10, 200] fp32
    float* __restrict__ out)                        // [T, B, 10] fp32
{
    const int b   = blockIdx.x;
    const int tid = threadIdx.x;
    __shared__ __align__(16) float wfoL[2000];          // [10][200]
    __shared__ unsigned char z3L[T_STEPS*200];          // 8 KB
    __shared__ float sL[400];                           // [40][10]

    for (int i = tid; i < 2000; i += 256) wfoL[i] = wfo[i];

    if (tid < 200) {
        const float* sx = c3 + (size_t)b*256 + tid;
        const size_t step = (size_t)BATCH*256;
        float v = 0.f, cur = 0.f;
        float x0 = sx[0], x1 = sx[step], x2 = sx[2*step], x3 = sx[3*step];

        #define SC2_SUB(J, XV)                                                \
            {                                                                 \
                float z = lif_update(XV, v, cur, 0.05f);                      \
                z3L[(t+J)*200 + tid] = (z > 0.5f) ? 1 : 0;                    \
                if (t + J + 4 < T_STEPS)                                      \
                    XV = sx[(size_t)(t + J + 4)*step];                        \
            }

        for (int t = 0; t < T_STEPS; t += 4) {
            SC2_SUB(0, x0);
            SC2_SUB(1, x1);
            SC2_SUB(2, x2);
            SC2_SUB(3, x3);
        }
        #undef SC2_SUB
    }
    __syncthreads();

    #pragma unroll
    for (int rep = 0; rep < 2; ++rep) {
        int task = tid + rep*256;
        if (task < 400) {
            int t = task / 10, n = task - t*10;
            float acc = 0.f;
            for (int k = 0; k < 200; k += 4) {
                uchar4 zb = *(const uchar4*)&z3L[t*200 + k];
                float4 wv = *(const float4*)&wfoL[n*200 + k];
                acc = __fadd_rn(acc, zb.x ? wv.x : 0.f);
                acc = __fadd_rn(acc, zb.y ? wv.y : 0.f);
                acc = __fadd_rn(acc, zb.z ? wv.z : 0.f);
                acc = __fadd_rn(acc, zb.w ? wv.w : 0.f);
            }
            sL[t*10 + n] = acc;
        }
    }
    __syncthreads();

    if (tid < 10) {
        float vo = 0.f, io = 0.f;
        for (int t = 0; t < T_STEPS; ++t) {
            float vd = __fadd_rn(vo, __fmul_rn(0.1f, __fsub_rn(io, vo)));
            out[((size_t)(t*BATCH + b))*10 + tid] = vd;
            io = __fadd_rn(__fmul_rn(0.8f, io), sL[t*10 + tid]);
            vo = vd;
        }
    }
}

extern "C" void kernel_launch(void* const* d_in, const int* in_sizes, int n_in,
                              void* d_out, int out_size, void* d_ws, size_t ws_size,
                              hipStream_t stream) {
    (void)in_sizes; (void)n_in; (void)out_size; (void)ws_size;
    const float* x   = (const float*)d_in[0];
    const float* w1  = (const float*)d_in[1];
    const float* w2  = (const float*)d_in[2];
    const float* wf1 = (const float*)d_in[3];
    const float* wf2 = (const float*)d_in[4];
    const float* wfo = (const float*)d_in[5];
    char* ws = (char*)d_ws;

    // ---- workspace layout (R9-proven overlay; peak 116.3 MB) ----
    // z1  u8 [0, 64,225,280)            10240 x 6272
    // s0  u8 [64,225,280, 106,168,320)  10240 x 4096 (dead after conv2)
    // W1q i8 [64,225,280, 73,859,072)   3 planes (overlays dead s0)
    // W2  fp16 [73,859,072, 74,383,360)
    // c2p fp32 [74,383,360, 116,326,400) [2][10240][512]
    // low region (z1 dead after fc1): z2 [0, 10,485,760) ;
    //   c3 [10,485,760, 20,971,520) [10240][256] fp32
    unsigned char*  z1    = (unsigned char*)(ws);
    unsigned char*  s0    = (unsigned char*)(ws + 64225280);
    signed char*    W1q   = (signed char*)(ws + 64225280);
    unsigned short* W2hi  = (unsigned short*)(ws + 73859072);
    float*          c2p   = (float*)(ws + 74383360);
    unsigned short* z2    = (unsigned short*)(ws);
    float*          c3    = (float*)(ws + 10485760);

    k_conv1<<<dim3(8, 256), 512, 0, stream>>>(x, w1, s0);
    k_conv2<<<1024, 256, 0, stream>>>(s0, w2, z1);

    k_pack_all<<<13056, 256, 0, stream>>>(wf1, wf2, W1q, W2hi);

    // fc1: single balanced 2560-block dispatch (5 blocks/CU, 2 waves)
    k_gemm_fc1<<<dim3(160, 8, 2), 256, 0, stream>>>(z1, W1q, c2p);
    k_lif_scan<<<dim3(2, 256), 256, 0, stream>>>(c2p, (size_t)5242880, z2, 512, 500, 0.1f, 1.0f);
    k_gemm_fc2<<<dim3(160, 4), 256, 0, stream>>>(z2, W2hi, c3);
    k_sc2_fcout_li<<<256, 256, 0, stream>>>(c3, wfo, (float*)d_out);
}